// Round 6
// baseline (2084.507 us; speedup 1.0000x reference)
//
#include <hip/hip_runtime.h>
#include <hip/hip_bf16.h>
#include <stdint.h>

#define LB 6
#define BB 32
#define SS 512
#define DD 512
#define HH 8
#define FF_ 2048
#define MM (BB*SS)   // 16384

typedef unsigned short u16;
typedef __attribute__((ext_vector_type(8))) short bf16x8;
typedef __attribute__((ext_vector_type(4))) float f32x4;

#define MFMA16(a,b,c) __builtin_amdgcn_mfma_f32_16x16x32_bf16((a),(b),(c),0,0,0)
#define GLD16(g, l) __builtin_amdgcn_global_load_lds( \
    (const __attribute__((address_space(1))) unsigned int*)(g), \
    (__attribute__((address_space(3))) unsigned int*)(l), 16, 0, 0)

__device__ __forceinline__ u16 f2b(float f){
  unsigned int u = __float_as_uint(f);
  u = u + 0x7FFFu + ((u >> 16) & 1u);
  return (u16)(u >> 16);
}

// gelu via sigmoid identity: 0.5x(1+tanh(u)) == x * sigmoid(2u)
__device__ __forceinline__ float gelu_f(float x){
  float u2 = 1.5957691216057308f * (x + 0.044715f * x * x * x);
  return x / (1.0f + __expf(-u2));
}

// ---------------- prep: h(fp32)=x, hbf=bf16(x) ----------------
__global__ __launch_bounds__(256) void k_prep(const float* __restrict__ x,
                                              float* __restrict__ h,
                                              u16* __restrict__ hb){
  int i = blockIdx.x * 256 + threadIdx.x;
  float4 v = ((const float4*)x)[i];
  ((float4*)h)[i] = v;
  uint2 p;
  p.x = (unsigned)f2b(v.x) | ((unsigned)f2b(v.y) << 16);
  p.y = (unsigned)f2b(v.z) | ((unsigned)f2b(v.w) << 16);
  ((uint2*)hb)[i] = p;
}

// ---------------- weight transpose + bf16 cast: out[n][k] = in[k][n] ----------------
__global__ __launch_bounds__(256) void k_wt(const float* __restrict__ in,
                                            u16* __restrict__ out, int K, int N){
  size_t ms = (size_t)K * N;
  in  += ms * blockIdx.z;
  out += ms * blockIdx.z;
  int n0 = blockIdx.x * 64, k0 = blockIdx.y * 64;
  __shared__ float tile[64][65];
  int t = threadIdx.x;
  int c = t & 63, rb = t >> 6;
  #pragma unroll
  for (int p = 0; p < 16; p++){
    int k = p * 4 + rb;
    tile[k][c] = in[(size_t)(k0 + k) * N + (n0 + c)];
  }
  __syncthreads();
  #pragma unroll
  for (int p = 0; p < 16; p++){
    int n = p * 4 + rb;
    out[(size_t)(n0 + n) * K + (k0 + c)] = f2b(tile[c][n]);
  }
}

// ================ GEMM: 128x128 tile, BK=32, 4 waves, single-buffer 2-barrier ================
// High-occupancy structure (16 KB LDS, ~90 VGPR -> 5-6 blocks/CU): inter-block overlap hides
// the per-block barrier drains (m114 mechanism) -- measured better than deep per-block
// pipelines at K<=2048 on this problem (R1: 81us vs R5 8-phase: 104us for FF1).
// LDS frag-major (16B slots): slot s holds (row16 = s&15 within frag, frag = s>>6,
// kchunk = (s>>4)&3); stage dest = wave-linear (slot t, t+256), frag read = frag*64 + lane
// slots -> both sides base + lane*16B, conflict-free, source address carries any permutation.
// EPI: 0 bf16, 1 fp32, 2 bias+gelu bf16, 3 bias fp32.  PERM: fused-QKV head-interleave fold.
template<int EPI, bool PERM>
__global__ __launch_bounds__(256) void k_gemm(
    const u16* __restrict__ A,
    const u16* __restrict__ Bq, const u16* __restrict__ Bk, const u16* __restrict__ Bv,
    const float* __restrict__ bias, float* __restrict__ outF, u16* __restrict__ outH,
    int N, int K)
{
  __shared__ u16 sA[4096], sB[4096];   // 8 KB + 8 KB
  const int t = threadIdx.x;
  const int w = t >> 6, lane = t & 63, lr = lane & 15, lh = lane >> 4;
  const int bm = blockIdx.x * 128;
  const int bn0 = blockIdx.y * 128;
  const int tz = PERM ? (bn0 >> 9) : 0;
  const int bn = PERM ? (bn0 & 511) : bn0;

  // staging source addressing: thread t covers slot t and slot t+256
  const int kch   = ((t >> 4) & 3) * 8;       // k element offset within 32-wide K-step
  const int arow0 = w * 16 + (t & 15);        // rows 0..63 (+64 for second GLD)
  int b0 = bn + arow0, b1 = bn + arow0 + 64;
  if (PERM){  // output col n <- source col (n&63)*8 + (n>>6)
    b0 = ((b0 & 63) << 3) | (b0 >> 6);
    b1 = ((b1 & 63) << 3) | (b1 >> 6);
  }
  const u16* Bsel = PERM ? (tz==0 ? Bq : tz==1 ? Bk : Bv) : Bq;
  const u16* gA0 = A + (size_t)(bm + arow0) * K + kch;
  const u16* gA1 = gA0 + (size_t)64 * K;
  const u16* gB0 = Bsel + (size_t)b0 * K + kch;
  const u16* gB1 = Bsel + (size_t)b1 * K + kch;
  const int wofs = w * 512;                   // u16 wave base (1 KB per wave region)

  const int iA = (w >> 1) * 4, iB = (w & 1) * 4;
  f32x4 acc[4][4];
  #pragma unroll
  for (int i = 0; i < 4; i++)
    #pragma unroll
    for (int j = 0; j < 4; j++) acc[i][j] = (f32x4){0.f,0.f,0.f,0.f};

  #pragma unroll 1
  for (int k0 = 0; k0 < K; k0 += 32){
    GLD16(gA0 + k0, sA + wofs);
    GLD16(gA1 + k0, sA + 2048 + wofs);
    GLD16(gB0 + k0, sB + wofs);
    GLD16(gB1 + k0, sB + 2048 + wofs);
    __syncthreads();
    bf16x8 af[4], bfr[4];
    #pragma unroll
    for (int i = 0; i < 4; i++) af[i]  = *(const bf16x8*)&sA[(iA + i)*512 + lane*8];
    #pragma unroll
    for (int j = 0; j < 4; j++) bfr[j] = *(const bf16x8*)&sB[(iB + j)*512 + lane*8];
    #pragma unroll
    for (int i = 0; i < 4; i++)
      #pragma unroll
      for (int j = 0; j < 4; j++)
        acc[i][j] = MFMA16(af[i], bfr[j], acc[i][j]);
    __syncthreads();
  }

  const int wr = (w >> 1) * 64, wc = (w & 1) * 64;
  #pragma unroll
  for (int i = 0; i < 4; i++){
    const int row = bm + wr + i*16 + lh*4;
    #pragma unroll
    for (int j = 0; j < 4; j++){
      const int col = bn + wc + j*16 + lr;
      float bv = (EPI >= 2) ? bias[col] : 0.f;
      #pragma unroll
      for (int r = 0; r < 4; r++){
        float v = acc[i][j][r];
        size_t o = (size_t)(row + r) * N + col;
        if (PERM) o += (size_t)tz * ((size_t)MM * DD);
        if (EPI == 0) outH[o] = f2b(v);
        else if (EPI == 1) outF[o] = v;
        else if (EPI == 2) outH[o] = f2b(gelu_f(v + bv));
        else outF[o] = v + bv;
      }
    }
  }
}

// ============== flash attention: QBLK=128, 8 waves, pipelined K-DMA / V-reg staging ==============
// Block = (qtile 128 rows, head, batch); 1D grid 1024 with XCD remap (h = L%8 so the 4 q-tiles
// of a (b,h) share an XCD L2).  Waves 0-3 stage V via regs (transpose+swizzle); waves 4-7 stage
// K via global_load_lds.  Next tile's loads are issued right after the barrier and consumed at
// the next barrier -> latency hidden under QK/softmax/PV.  One __syncthreads per kv-tile.
__global__ __launch_bounds__(512) void k_attn(const u16* __restrict__ Q, const u16* __restrict__ Kp,
                                              const u16* __restrict__ V, u16* __restrict__ O){
  const int L = blockIdx.x;
  const int hh = L & 7, qt = (L >> 3) & 3, b = L >> 5;
  __shared__ u16 Qs[8192];      // [128][64] row-xor-swizzled
  __shared__ u16 Ks[2][4096];   // [64][64]  row-xor-swizzled, double buffered
  __shared__ u16 Vt[2][4096];   // [dk][kv]  double-key swizzled, double buffered
  __shared__ u16 Ps[8192];      // [128][64] per-wave rows
  const int t = threadIdx.x, w = t >> 6, lane = t & 63, lr = lane & 15, lh = lane >> 4;
  const size_t base = ((size_t)b * SS) * DD + (size_t)hh * 64;

  {
    const int srow = t >> 3;
    const int gcol = (((t & 7) ^ (srow & 7)) << 3);
    const u16* g = Q + base + (size_t)(qt*128 + srow) * DD + gcol;
    GLD16(g,                 Qs + w*512);
    GLD16(g + (size_t)64*DD, Qs + 4096 + w*512);
  }
  const int vdk0 = (t & 7) * 8, vkv = ((t >> 3) & 31) * 2;
  const int srow2 = ((w & 3) * 8) + (lane >> 3);
  const int gcol2 = (((lane & 7) ^ (srow2 & 7)) << 3);
  uint4 rv0, rv1;
  if (w < 4){
    const u16* g = V + base + (size_t)vkv * DD + vdk0;
    rv0 = *(const uint4*)g; rv1 = *(const uint4*)(g + DD);
  } else {
    const u16* g = Kp + base + (size_t)srow2 * DD + gcol2;
    GLD16(g,                 Ks[0] + (w-4)*512);
    GLD16(g + (size_t)32*DD, Ks[0] + 2048 + (w-4)*512);
  }

  float mreg[4], lreg[4];
  f32x4 ofr[4];
  #pragma unroll
  for (int r = 0; r < 4; r++){ mreg[r] = -1e30f; lreg[r] = 0.f; }
  #pragma unroll
  for (int j = 0; j < 4; j++) ofr[j] = (f32x4){0.f,0.f,0.f,0.f};

  const int qswz = (lr & 7) << 3;

  for (int kt = 0; kt < 8; kt++){
    const int bix = kt & 1;
    if (w < 4){
      const u16* e0 = (const u16*)&rv0;
      const u16* e1 = (const u16*)&rv1;
      #pragma unroll
      for (int i = 0; i < 8; i++){
        int dk = vdk0 + i;
        int sw = ((((dk >> 3) ^ dk) & 7) << 3);
        *(unsigned int*)&Vt[bix][dk*64 + (vkv ^ sw)] =
            (unsigned int)e0[i] | ((unsigned int)e1[i] << 16);
      }
    }
    __syncthreads();

    if (kt < 7){
      if (w < 4){
        const u16* g = V + base + (size_t)((kt+1)*64 + vkv) * DD + vdk0;
        rv0 = *(const uint4*)g; rv1 = *(const uint4*)(g + DD);
      } else {
        const u16* g = Kp + base + (size_t)((kt+1)*64 + srow2) * DD + gcol2;
        GLD16(g,                 Ks[bix^1] + (w-4)*512);
        GLD16(g + (size_t)32*DD, Ks[bix^1] + 2048 + (w-4)*512);
      }
    }

    bf16x8 a0 = *(const bf16x8*)&Qs[(w*16+lr)*64 + ((lh*8) ^ qswz)];
    bf16x8 a1 = *(const bf16x8*)&Qs[(w*16+lr)*64 + ((32 + lh*8) ^ qswz)];
    f32x4 sc[4];
    #pragma unroll
    for (int j = 0; j < 4; j++){
      bf16x8 b0 = *(const bf16x8*)&Ks[bix][(j*16+lr)*64 + ((lh*8) ^ qswz)];
      bf16x8 b1 = *(const bf16x8*)&Ks[bix][(j*16+lr)*64 + ((32 + lh*8) ^ qswz)];
      f32x4 z = (f32x4){0.f,0.f,0.f,0.f};
      z = MFMA16(a0, b0, z);
      z = MFMA16(a1, b1, z);
      sc[j] = z;
    }

    float pr[4][4];
    float esc[4];
    #pragma unroll
    for (int r = 0; r < 4; r++){
      float mx = fmaxf(fmaxf(sc[0][r], sc[1][r]), fmaxf(sc[2][r], sc[3][r]));
      mx = fmaxf(mx, __shfl_xor(mx, 1));
      mx = fmaxf(mx, __shfl_xor(mx, 2));
      mx = fmaxf(mx, __shfl_xor(mx, 4));
      mx = fmaxf(mx, __shfl_xor(mx, 8));
      mx *= 0.125f;
      float m2 = fmaxf(mreg[r], mx);
      float scl = __expf(mreg[r] - m2);
      mreg[r] = m2;
      float s = 0.f;
      #pragma unroll
      for (int j = 0; j < 4; j++){
        float p = __expf(sc[j][r]*0.125f - m2);
        pr[j][r] = p;
        s += p;
      }
      s += __shfl_xor(s, 1);
      s += __shfl_xor(s, 2);
      s += __shfl_xor(s, 4);
      s += __shfl_xor(s, 8);
      lreg[r] = lreg[r]*scl + s;
      esc[r] = scl;
    }

    #pragma unroll
    for (int j = 0; j < 4; j++)
      #pragma unroll
      for (int r = 0; r < 4; r++){
        int prow = w*16 + lh*4 + r;
        int pcol = j*16 + lr;
        Ps[prow*64 + (pcol ^ (((lh*4 + r) & 7) << 3))] = f2b(pr[j][r]);
      }

    #pragma unroll
    for (int j = 0; j < 4; j++)
      #pragma unroll
      for (int r = 0; r < 4; r++) ofr[j][r] *= esc[r];

    bf16x8 pa0 = *(const bf16x8*)&Ps[(w*16+lr)*64 + ((lh*8) ^ qswz)];
    bf16x8 pa1 = *(const bf16x8*)&Ps[(w*16+lr)*64 + ((32 + lh*8) ^ qswz)];
    #pragma unroll
    for (int j = 0; j < 4; j++){
      int dkr = j*16 + lr;
      int sw = ((((dkr >> 3) ^ dkr) & 7) << 3);
      bf16x8 v0 = *(const bf16x8*)&Vt[bix][dkr*64 + ((lh*8) ^ sw)];
      bf16x8 v1 = *(const bf16x8*)&Vt[bix][dkr*64 + ((32 + lh*8) ^ sw)];
      ofr[j] = MFMA16(pa0, v0, ofr[j]);
      ofr[j] = MFMA16(pa1, v1, ofr[j]);
    }
  }

  #pragma unroll
  for (int j = 0; j < 4; j++)
    #pragma unroll
    for (int r = 0; r < 4; r++){
      float v = ofr[j][r] / lreg[r];
      O[base + (size_t)(qt*128 + w*16 + lh*4 + r) * DD + j*16 + lr] = f2b(v);
    }
}

// ---------------- fused residual add + LayerNorm: wave per row, float4 loads ----------------
__global__ __launch_bounds__(256) void k_ln(const float* __restrict__ hin, const float* __restrict__ add,
    const float* __restrict__ g, const float* __restrict__ be,
    float* __restrict__ hout, u16* __restrict__ hb){
  const int w = threadIdx.x >> 6, lane = threadIdx.x & 63;
  const size_t row = (size_t)blockIdx.x * 4 + w;
  const size_t base = row * DD + lane * 8;
  float4 xa = *(const float4*)&hin[base];
  float4 xb = *(const float4*)&hin[base + 4];
  float4 aa = *(const float4*)&add[base];
  float4 ab = *(const float4*)&add[base + 4];
  float v[8] = { xa.x+aa.x, xa.y+aa.y, xa.z+aa.z, xa.w+aa.w,
                 xb.x+ab.x, xb.y+ab.y, xb.z+ab.z, xb.w+ab.w };
  float s = 0.f, q = 0.f;
  #pragma unroll
  for (int e = 0; e < 8; e++){ s += v[e]; q += v[e]*v[e]; }
  #pragma unroll
  for (int m = 32; m >= 1; m >>= 1){ s += __shfl_xor(s, m); q += __shfl_xor(q, m); }
  float mean = s * (1.f/512.f);
  float var  = q * (1.f/512.f) - mean*mean;
  float rstd = rsqrtf(var + 1e-5f);
  float4 g0 = *(const float4*)&g[lane*8],  g1 = *(const float4*)&g[lane*8+4];
  float4 b0 = *(const float4*)&be[lane*8], b1 = *(const float4*)&be[lane*8+4];
  float gv[8] = {g0.x,g0.y,g0.z,g0.w,g1.x,g1.y,g1.z,g1.w};
  float bv[8] = {b0.x,b0.y,b0.z,b0.w,b1.x,b1.y,b1.z,b1.w};
  float o[8];
  #pragma unroll
  for (int e = 0; e < 8; e++) o[e] = gv[e] * ((v[e]-mean)*rstd) + bv[e];
  *(float4*)&hout[base]     = make_float4(o[0],o[1],o[2],o[3]);
  *(float4*)&hout[base + 4] = make_float4(o[4],o[5],o[6],o[7]);
  uint4 pk;
  pk.x = (unsigned)f2b(o[0]) | ((unsigned)f2b(o[1])<<16);
  pk.y = (unsigned)f2b(o[2]) | ((unsigned)f2b(o[3])<<16);
  pk.z = (unsigned)f2b(o[4]) | ((unsigned)f2b(o[5])<<16);
  pk.w = (unsigned)f2b(o[6]) | ((unsigned)f2b(o[7])<<16);
  *(uint4*)&hb[base] = pk;
}

// ---------------- launch ----------------
extern "C" void kernel_launch(void* const* d_in, const int* in_sizes, int n_in,
                              void* d_out, int out_size, void* d_ws, size_t ws_size,
                              hipStream_t stream){
  const float* x   = (const float*)d_in[0];
  const float* WQ  = (const float*)d_in[1];
  const float* WK  = (const float*)d_in[2];
  const float* WV  = (const float*)d_in[3];
  const float* WO  = (const float*)d_in[4];
  const float* K1  = (const float*)d_in[5];
  const float* B1  = (const float*)d_in[6];
  const float* K2  = (const float*)d_in[7];
  const float* B2  = (const float*)d_in[8];
  const float* G1  = (const float*)d_in[9];
  const float* BE1 = (const float*)d_in[10];
  const float* G2  = (const float*)d_in[11];
  const float* BE2 = (const float*)d_in[12];
  float* hF = (float*)d_out;

  char* wp = (char*)d_ws;
  size_t off = 0;
  auto a16 = [&](size_t elems)->u16*{ u16* p = (u16*)(wp + off); off += elems*sizeof(u16); return p; };
  u16* WQt = a16((size_t)LB*DD*DD);
  u16* WKt = a16((size_t)LB*DD*DD);
  u16* WVt = a16((size_t)LB*DD*DD);
  u16* WOt = a16((size_t)LB*DD*DD);
  u16* K1t = a16((size_t)LB*DD*FF_);
  u16* K2t = a16((size_t)LB*DD*FF_);
  u16* hbf = a16((size_t)MM*DD);
  u16* qbf = a16((size_t)MM*DD);   // qbf,kbf,vbf contiguous (PERM epilogue relies on it)
  u16* kbf = a16((size_t)MM*DD);
  u16* vbf = a16((size_t)MM*DD);
  u16* abf = a16((size_t)MM*DD);
  u16* ff1 = qbf;  // alias: q/k/v/a dead when ff1 (MM x FF_) is live
  float* tmpF = (float*)(wp + off); off += (size_t)MM*DD*sizeof(float);
  (void)ws_size; (void)in_sizes; (void)n_in; (void)out_size;

  k_prep<<<MM*DD/4/256, 256, 0, stream>>>(x, hF, hbf);
  k_wt<<<dim3(8,8,LB),        256, 0, stream>>>(WQ, WQt, DD, DD);
  k_wt<<<dim3(8,8,LB),        256, 0, stream>>>(WK, WKt, DD, DD);
  k_wt<<<dim3(8,8,LB),        256, 0, stream>>>(WV, WVt, DD, DD);
  k_wt<<<dim3(8,8,LB),        256, 0, stream>>>(WO, WOt, DD, DD);
  k_wt<<<dim3(FF_/64,8,LB),   256, 0, stream>>>(K1, K1t, DD, FF_);
  k_wt<<<dim3(8,FF_/64,LB),   256, 0, stream>>>(K2, K2t, FF_, DD);

  for (int l = 0; l < LB; l++){
    const u16* wq = WQt + (size_t)l*DD*DD;
    const u16* wk = WKt + (size_t)l*DD*DD;
    const u16* wv = WVt + (size_t)l*DD*DD;
    const u16* wo = WOt + (size_t)l*DD*DD;
    const u16* k1 = K1t + (size_t)l*DD*FF_;
    const u16* k2 = K2t + (size_t)l*DD*FF_;

    // fused QKV: 16384 x 1536 (PERM head-fold in B staging), 128^2 tiles
    k_gemm<0,true ><<<dim3(128,12), 256, 0, stream>>>(hbf, wq, wk, wv, nullptr, nullptr, qbf, DD, DD);
    k_attn<<<dim3(1024), 512, 0, stream>>>(qbf, kbf, vbf, abf);
    k_gemm<1,false><<<dim3(128,4),  256, 0, stream>>>(abf, wo, wo, wo, nullptr, tmpF, nullptr, DD, DD);
    k_ln<<<MM/4, 256, 0, stream>>>(hF, tmpF, G1 + l*DD, BE1 + l*DD, hF, hbf);
    k_gemm<2,false><<<dim3(128,16), 256, 0, stream>>>(hbf, k1, k1, k1, B1 + (size_t)l*FF_, nullptr, ff1, FF_, DD);
    k_gemm<3,false><<<dim3(128,4),  256, 0, stream>>>(ff1, k2, k2, k2, B2 + l*DD, tmpF, nullptr, DD, FF_);
    k_ln<<<MM/4, 256, 0, stream>>>(hF, tmpF, G2 + l*DD, BE2 + l*DD, hF, hbf);
  }
}